// Round 2
// baseline (290.696 us; speedup 1.0000x reference)
//
#include <hip/hip_runtime.h>

// Problem constants: x [L,B,E], H heads, head dim 64.
#define L_DIM 1024
#define B_DIM 8
#define E_DIM 1024
#define H_DIM 16
#define HD 64
#define BH_DIM (B_DIM * H_DIM)  // 128

typedef float f32x4 __attribute__((ext_vector_type(4)));
typedef _Float16 f16_t;
typedef f16_t f16x4 __attribute__((ext_vector_type(4)));
typedef f16_t f16x8 __attribute__((ext_vector_type(8)));

// async global->LDS, 16 B per lane (m97 pattern): wave-uniform base + lane*16.
static __device__ __forceinline__ void gld16(const void* g, void* l) {
  __builtin_amdgcn_global_load_lds(
      (const __attribute__((address_space(1))) unsigned int*)g,
      (__attribute__((address_space(3))) unsigned int*)l, 16, 0, 0);
}

// fp32 -> f16 pre-convert of x, w_in, w_out (grid-stride over float4 units).
__global__ __launch_bounds__(256) void convert_f16(
    const float* __restrict__ x, const float* __restrict__ wi,
    const float* __restrict__ wo, f16_t* __restrict__ x16,
    f16_t* __restrict__ wi16, f16_t* __restrict__ wo16) {
  const int NX = (L_DIM * B_DIM * E_DIM) / 4;   // 2097152
  const int NWI = (3 * E_DIM * E_DIM) / 4;      // 786432
  const int NWO = (E_DIM * E_DIM) / 4;          // 262144
  const int total = NX + NWI + NWO;
  for (int i = blockIdx.x * blockDim.x + threadIdx.x; i < total;
       i += gridDim.x * blockDim.x) {
    const float4* src; f16_t* dst; int j;
    if (i < NX)            { src = (const float4*)x;  dst = x16;  j = i; }
    else if (i < NX + NWI) { src = (const float4*)wi; dst = wi16; j = i - NX; }
    else                   { src = (const float4*)wo; dst = wo16; j = i - NX - NWI; }
    const float4 v = src[j];
    f16x4 h = {(f16_t)v.x, (f16_t)v.y, (f16_t)v.z, (f16_t)v.w};
    *(f16x4*)(dst + (size_t)j * 4) = h;
  }
}

// ---------------------------------------------------------------------------
// QKV GEMM, 256x256, BK=64, 8 waves.  Round-2 change: LDS reads are software-
// pipelined ONE PHASE AHEAD with counted lgkmcnt (never 0 in the loop), so the
// LDS serve time of phase p+1's ds_reads hides under phase p's MFMA cluster.
// Round-1 post-mortem showed per-phase time = LDS-window + MFMA-window
// SERIALIZED (1387 cyc ~= 730 + 621): the old lgkmcnt(0)-before-MFMA exposed
// the full LDS latency every phase.
//
// Per phase (t,g): issue A-frags for phase g+1 (4 ds_read_b128); at g2/g3
// also issue half the next tile's B-frags (4); stage one half-tile (2 gld16);
// s_waitcnt lgkmcnt(n_just_issued) -> clears only the PREVIOUS phase's reads;
// 16 MFMA under setprio; counted vmcnt at g1 (publish B(t+1)) / g2 (publish
// A(t+1)); ONE s_barrier; sched_barrier(0) after it (publication-critical
// reads must not hoist into the VMW..barrier gap - other waves' staging!).
//
// Per-thread gld16 in flight (2 per phase): enter tile t with 4 [B(t+1)];
// g0 +2 A(t+1)h0 ->6; g1 +2 ->8, vmcnt(4) leaves A(t+1):4; g2 +2 B(t+2)h0 ->6,
// vmcnt(2) leaves B(t+2)h0:2; g3 +2 ->4 = entry state of tile t+1.  Never 0.
// lgkm: issued per phase g0:4 g1:4 g2:8 g3:8 -> wait lgkmcnt(4/4/8/8).
// ---------------------------------------------------------------------------

#define LGKM(n) do { asm volatile("s_waitcnt lgkmcnt(" #n ")" ::: "memory");  \
                     __builtin_amdgcn_sched_barrier(0); } while (0)
#define VMW(n) asm volatile("s_waitcnt vmcnt(" #n ")" ::: "memory")

// stage one 128x64 half-tile (16 KB) = 2 x gld16 per thread (512 threads).
#define STAGE_A(d, ht, kt) do {                                              \
    gld16(Asrc + (size_t)(ht) * (128 * 1024) + (kt) * 64,                    \
          &As[(d) * 16384 + (ht) * 8192 + tid * 8]);                         \
    gld16(Asrc + (size_t)(ht) * (128 * 1024) + 64 * 1024 + (kt) * 64,        \
          &As[(d) * 16384 + (ht) * 8192 + 4096 + tid * 8]);                  \
  } while (0)
#define STAGE_B(d, ht, kt) do {                                              \
    gld16(Bsrc + (size_t)(ht) * (128 * 1024) + (kt) * 64,                    \
          &Bs[(d) * 16384 + (ht) * 8192 + tid * 8]);                         \
    gld16(Bsrc + (size_t)(ht) * (128 * 1024) + 64 * 1024 + (kt) * 64,        \
          &Bs[(d) * 16384 + (ht) * 8192 + 4096 + tid * 8]);                  \
  } while (0)

// swizzled frag pointer: logical byte = r*128 + ks*64 + quad*16, physical
// XORs (r&7)<<4.  r always = base + l16 so r&7 == l16&7.  (bank conflicts
// measured 0 with this in round 1.)
static __device__ __forceinline__ const f16x8* fp16frag(
    const f16_t* tile, int r, int ks, int quad, int l16) {
  const int bo = (r * 128 + ks * 64 + quad * 16) ^ ((l16 & 7) << 4);
  return (const f16x8*)((const char*)tile + bo);
}

// fill half the next tile's B frags (c0..c0+1, both k-slices) from buf nb.
#define BFF(nb, bfF, c0) do {                                                \
    _Pragma("unroll") for (int cc_ = 0; cc_ < 2; ++cc_)                      \
      _Pragma("unroll") for (int ks_ = 0; ks_ < 2; ++ks_)                    \
        bfF[(c0) + cc_][ks_] = *fp16frag(&Bs[(nb) * 16384],                  \
            wc * 64 + ((c0) + cc_) * 16 + l16, ks_, quad, l16);              \
  } while (0)

// one phase: af-fill (next phase, from buf asrc), optional bf-fill, stage,
// counted lgkm, 16 MFMA on af_use/bf_use, counted vm-wait, barrier.
#define PH(g, afU, afF, asrc, bfU, BFFILL_STMT, STAGE_STMT, LGW, ENDW) do {  \
    _Pragma("unroll") for (int f_ = 0; f_ < 2; ++f_)                         \
      _Pragma("unroll") for (int ks_ = 0; ks_ < 2; ++ks_)                    \
        afF[f_][ks_] = *fp16frag(&As[(asrc) * 16384],                        \
            wr * 128 + (((((g) + 1) & 3) * 2) + f_) * 16 + l16,              \
            ks_, quad, l16);                                                 \
    BFFILL_STMT;                                                             \
    STAGE_STMT;                                                              \
    LGW;                                                                     \
    __builtin_amdgcn_s_setprio(1);                                           \
    _Pragma("unroll") for (int f_ = 0; f_ < 2; ++f_)                         \
      _Pragma("unroll") for (int c_ = 0; c_ < 4; ++c_)                       \
        _Pragma("unroll") for (int ks_ = 0; ks_ < 2; ++ks_)                  \
          acc[(g) * 2 + f_][c_] = __builtin_amdgcn_mfma_f32_16x16x32_f16(    \
              afU[f_][ks_], bfU[c_][ks_], acc[(g) * 2 + f_][c_], 0, 0, 0);   \
    __builtin_amdgcn_s_setprio(0);                                           \
    __builtin_amdgcn_sched_barrier(0);                                       \
    ENDW;                                                                    \
    __builtin_amdgcn_s_barrier();                                            \
    __builtin_amdgcn_sched_barrier(0);                                       \
  } while (0)

__global__ __launch_bounds__(512, 2) void gemm_qkv(
    const f16_t* __restrict__ A, const f16_t* __restrict__ B,
    const float* __restrict__ bias, f16_t* __restrict__ Oq,
    f16_t* __restrict__ Ok, f16_t* __restrict__ Ov) {
  constexpr int K = 1024;
  constexpr int NT = K / 64;  // 16 K-tiles
  __shared__ __align__(16) f16_t As[2 * 16384];  // 64 KB: dbuf x 256x64
  __shared__ __align__(16) f16_t Bs[2 * 16384];  // 64 KB

  const int tid = threadIdx.x;
  const int lane = tid & 63;
  const int w = tid >> 6;       // 0..7
  const int wr = w >> 2;        // M half
  const int wc = w & 3;         // N quarter
  const int quad = lane >> 4;
  const int l16 = lane & 15;

  // XCD-aware bijective swizzle: 384 wg = 8 XCDs x 48.
  const int bid = blockIdx.x;
  const int wg = (bid & 7) * 48 + (bid >> 3);
  const int tn = wg >> 5;       // 0..11
  const int tm = wg & 31;       // 0..31
  const int m0 = tm * 256;
  const int n0 = tn * 256;

  // staging: thread covers row srow (of a 128-row half), swizzled col block.
  const int srow = tid >> 3;
  const int scol = ((tid & 7) ^ (srow & 7)) * 8;  // pre-swizzled global col
  const f16_t* Asrc = A + (size_t)(m0 + srow) * K + scol;
  const f16_t* Bsrc = B + (size_t)(n0 + srow) * K + scol;

  f32x4 acc[8][4] = {};
  f16x8 afA[2][2], afB[2][2];   // phase-ping-pong A frags
  f16x8 bfX[4][2], bfY[4][2];   // tile-ping-pong B frags

  // Prologue: A(0), B(0), B(1); vmcnt(4) -> A(0)+B(0) done, B(1) in flight.
  STAGE_A(0, 0, 0); STAGE_A(0, 1, 0);
  STAGE_B(0, 0, 0); STAGE_B(0, 1, 0);
  STAGE_B(1, 0, 1); STAGE_B(1, 1, 1);
  VMW(4);
  __builtin_amdgcn_s_barrier();
  __builtin_amdgcn_sched_barrier(0);
  // Prime afA (tile0 phase g0) and bfX (tile0 B) - cleared by (0,g0)'s LGKM(4).
#pragma unroll
  for (int f_ = 0; f_ < 2; ++f_)
#pragma unroll
    for (int ks_ = 0; ks_ < 2; ++ks_)
      afA[f_][ks_] = *fp16frag(&As[0], wr * 128 + f_ * 16 + l16, ks_, quad, l16);
  BFF(0, bfX, 0); BFF(0, bfX, 2);

  for (int it = 0; it < 8; ++it) {
    const int t1 = 2 * it + 1;
    const int ta = (2 * it + 2 < NT) ? 2 * it + 2 : NT - 1;  // clamped: keeps
    const int tb = (2 * it + 3 < NT) ? 2 * it + 3 : NT - 1;  // wait counts fixed
    // tile t0 = 2*it (buf0, bfX); af fills from buf0 until g3 (-> buf1)
    PH(0, afA, afB, 0, bfX, , STAGE_A(1, 0, t1), LGKM(4), );
    PH(1, afB, afA, 0, bfX, , STAGE_A(1, 1, t1), LGKM(4), VMW(4));
    PH(2, afA, afB, 0, bfX, BFF(1, bfY, 0), STAGE_B(0, 0, ta), LGKM(8), VMW(2));
    PH(3, afB, afA, 1, bfX, BFF(1, bfY, 2), STAGE_B(0, 1, ta), LGKM(8), );
    // tile t1 (buf1, bfY); af fills from buf1 until g3 (-> buf0)
    PH(0, afA, afB, 1, bfY, , STAGE_A(0, 0, ta), LGKM(4), );
    PH(1, afB, afA, 1, bfY, , STAGE_A(0, 1, ta), LGKM(4), VMW(4));
    PH(2, afA, afB, 1, bfY, BFF(0, bfX, 0), STAGE_B(1, 0, tb), LGKM(8), VMW(2));
    PH(3, afB, afA, 0, bfY, BFF(0, bfX, 2), STAGE_B(1, 1, tb), LGKM(8), );
  }

  // Epilogue: C/D layout col=l16, row=quad*4+r.  q/k/v scatter as before.
#pragma unroll
  for (int i = 0; i < 8; ++i) {
    const int mbase = m0 + wr * 128 + i * 16 + quad * 4;
#pragma unroll
    for (int c = 0; c < 4; ++c) {
      const int n = n0 + wc * 64 + c * 16 + l16;
      const float bv = bias[n];
      const int chunk = n >> 10;      // 0=q 1=k 2=v (uniform per 16-wide frag)
      const int e = n & 1023;
      const int h = e >> 6;
      const int d = e & 63;
#pragma unroll
      for (int r = 0; r < 4; ++r) {
        const int m = mbase + r;
        const int l = m >> 3, b = m & 7;          // row m = l*B + b
        const size_t idx = ((size_t)(b * H_DIM + h) * L_DIM + l) * HD + d;
        const float val = acc[i][c][r] + bv;
        if (chunk == 0)      Oq[idx] = (f16_t)(val * 0.125f);  // 64^-0.5
        else if (chunk == 1) Ok[idx] = (f16_t)val;
        else                 Ov[idx] = (f16_t)val;
      }
    }
  }
}

// ---------------------------------------------------------------------------
// Out-proj GEMM kept on the m97 128x128 structure (N=1024 -> only 128 blocks
// at 256^2, half the GPU idle; revisit later).
// ---------------------------------------------------------------------------
template <int MODE>
__global__ __launch_bounds__(256, 2) void gemm_f16(
    const f16_t* __restrict__ A, const f16_t* __restrict__ B,
    const float* __restrict__ bias, void* __restrict__ O0v,
    void* __restrict__ O1v, void* __restrict__ O2v) {
  constexpr int K = 1024;
  __shared__ __align__(16) f16_t As[128 * 32];
  __shared__ __align__(16) f16_t Bs[128 * 32];

  const int tid = threadIdx.x;
  const int lane = tid & 63;
  const int wave = tid >> 6;
  const int wm = (wave & 1) * 64;
  const int wn = (wave >> 1) * 64;
  const int quad = lane >> 4;
  const int l16 = lane & 15;
  const int m0 = blockIdx.y * 128;
  const int n0 = blockIdx.x * 128;

  const int cr = tid >> 2;
  const int cc = (tid & 3) * 8;

  f32x4 acc[4][4] = {};

  for (int k0 = 0; k0 < K; k0 += 32) {
    __syncthreads();
    gld16(A + (size_t)(m0 + cr) * K + k0 + cc,      As + tid * 8);
    gld16(A + (size_t)(m0 + 64 + cr) * K + k0 + cc, As + 2048 + tid * 8);
    gld16(B + (size_t)(n0 + cr) * K + k0 + cc,      Bs + tid * 8);
    gld16(B + (size_t)(n0 + 64 + cr) * K + k0 + cc, Bs + 2048 + tid * 8);
    __syncthreads();

    f16x8 af[4], bfr[4];
#pragma unroll
    for (int t = 0; t < 4; ++t) {
      af[t]  = *(const f16x8*)&As[(wm + t * 16 + l16) * 32 + quad * 8];
      bfr[t] = *(const f16x8*)&Bs[(wn + t * 16 + l16) * 32 + quad * 8];
    }
#pragma unroll
    for (int i = 0; i < 4; ++i)
#pragma unroll
      for (int j = 0; j < 4; ++j)
        acc[i][j] = __builtin_amdgcn_mfma_f32_16x16x32_f16(af[i], bfr[j], acc[i][j], 0, 0, 0);
  }

#pragma unroll
  for (int i = 0; i < 4; ++i) {
    const int mbase = m0 + wm + i * 16 + quad * 4;
#pragma unroll
    for (int j = 0; j < 4; ++j) {
      const int n = n0 + wn + j * 16 + l16;
      const float bv = bias[n];
      if (MODE == 0) {
        f16_t* O0 = (f16_t*)O0v; f16_t* O1 = (f16_t*)O1v; f16_t* O2 = (f16_t*)O2v;
        const int chunk = n >> 10;
        const int e = n & 1023;
        const int h = e >> 6;
        const int d = e & 63;
#pragma unroll
        for (int r = 0; r < 4; ++r) {
          const int m = mbase + r;
          const int l = m >> 3, b = m & 7;
          const size_t idx = ((size_t)(b * H_DIM + h) * L_DIM + l) * HD + d;
          const float val = acc[i][j][r] + bv;
          if (chunk == 0)      O0[idx] = (f16_t)(val * 0.125f);
          else if (chunk == 1) O1[idx] = (f16_t)val;
          else                 O2[idx] = (f16_t)val;
        }
      } else {
        float* O0 = (float*)O0v;
#pragma unroll
        for (int r = 0; r < 4; ++r) {
          const int m = mbase + r;
          O0[(size_t)m * E_DIM + n] = acc[i][j][r] + bv;
        }
      }
    }
  }
}

// Attention v5 (unchanged this round): all-f16, 64 q per wave, S^T = K.Q^T
// with permuted key->row mapping, in-register P, V^T staged in-kernel.
__global__ __launch_bounds__(256, 2) void attn_f16(
    const f16_t* __restrict__ Q, const f16_t* __restrict__ K,
    const f16_t* __restrict__ V, f16_t* __restrict__ O) {
  constexpr int KSTR = 70;
  __shared__ __align__(16) f16_t Ks[64 * KSTR];
  __shared__ __align__(16) f16_t Vs[64 * KSTR];
  __shared__ float Ls[4][64];

  const int tid = threadIdx.x;
  const int lane = tid & 63;
  const int w = tid >> 6;
  const int quad = lane >> 4;
  const int l16 = lane & 15;
  const int bh = blockIdx.y;
  const int q0 = blockIdx.x * 256 + w * 64;

  const f16_t* Qb = Q + (size_t)bh * L_DIM * HD;
  const f16_t* Kb = K + (size_t)bh * L_DIM * HD;
  const f16_t* Vb = V + (size_t)bh * L_DIM * HD;

  f16x8 qf[4][2];
#pragma unroll
  for (int nt = 0; nt < 4; ++nt)
#pragma unroll
    for (int kc = 0; kc < 2; ++kc)
      qf[nt][kc] = *(const f16x8*)(Qb + (size_t)(q0 + nt * 16 + l16) * HD + kc * 32 + quad * 8);

  f32x4 oacc[4][4] = {};
  float rsum[4] = {0.0f, 0.0f, 0.0f, 0.0f};

  const int sr = tid >> 3;
  const int sc8 = (tid & 7) * 8;
  const int va = tid & 31;
  const int vg = tid >> 5;
  const int rA = (l16 >> 2) * 8 + (l16 & 3);

  for (int kt = 0; kt < 16; ++kt) {
    __syncthreads();
    {
      const f16_t* kp = Kb + (size_t)(kt * 64) * HD;
#pragma unroll
      for (int rr = 0; rr < 2; ++rr) {
        const int row = sr + rr * 32;
        *(f16x8*)&Ks[row * KSTR + sc8] = *(const f16x8*)(kp + (size_t)row * HD + sc8);
      }
      const f16_t* vp = Vb + (size_t)(kt * 64 + vg * 8) * HD + 2 * va;
      unsigned int vd[8];
#pragma unroll
      for (int i = 0; i < 8; ++i) vd[i] = *(const unsigned int*)(vp + (size_t)i * HD);
      union { unsigned int u[4]; f16x8 v; } lo, hi;
#pragma unroll
      for (int i = 0; i < 4; ++i) {
        lo.u[i] = (vd[2 * i] & 0xffffu) | (vd[2 * i + 1] << 16);
        hi.u[i] = (vd[2 * i] >> 16) | (vd[2 * i + 1] & 0xffff0000u);
      }
      *(f16x8*)&Vs[(2 * va) * KSTR + vg * 8] = lo.v;
      *(f16x8*)&Vs[(2 * va + 1) * KSTR + vg * 8] = hi.v;
    }
    __syncthreads();

#pragma unroll
    for (int c = 0; c < 2; ++c) {
      f32x4 sc[2][4] = {};
#pragma unroll
      for (int h = 0; h < 2; ++h) {
        const int row = c * 32 + h * 4 + rA;
#pragma unroll
        for (int kc = 0; kc < 2; ++kc) {
          const f16x8 ka = *(const f16x8*)&Ks[row * KSTR + kc * 32 + quad * 8];
#pragma unroll
          for (int nt = 0; nt < 4; ++nt)
            sc[h][nt] = __builtin_amdgcn_mfma_f32_16x16x32_f16(ka, qf[nt][kc], sc[h][nt], 0, 0, 0);
        }
      }

      f16x8 pa[4];
#pragma unroll
      for (int nt = 0; nt < 4; ++nt)
#pragma unroll
        for (int h = 0; h < 2; ++h)
#pragma unroll
          for (int r = 0; r < 4; ++r) {
            const float e = __expf(sc[h][nt][r]);
            rsum[nt] += e;
            pa[nt][h * 4 + r] = (f16_t)e;
          }

#pragma unroll
      for (int nd = 0; nd < 4; ++nd) {
        const f16x8 vb = *(const f16x8*)&Vs[(nd * 16 + l16) * KSTR + c * 32 + quad * 8];
#pragma unroll
        for (int nt = 0; nt < 4; ++nt)
          oacc[nt][nd] = __builtin_amdgcn_mfma_f32_16x16x32_f16(pa[nt], vb, oacc[nt][nd], 0, 0, 0);
      }
    }
  }

#pragma unroll
  for (int nt = 0; nt < 4; ++nt) {
    float rs = rsum[nt];
    rs += __shfl_xor(rs, 16); rs += __shfl_xor(rs, 32);
    if (quad == 0) Ls[w][nt * 16 + l16] = rs;
  }
  asm volatile("s_waitcnt lgkmcnt(0)" ::: "memory");

  const int b = bh >> 4;
  const int h = bh & 15;
#pragma unroll
  for (int nt = 0; nt < 4; ++nt)
#pragma unroll
    for (int r = 0; r < 4; ++r) {
      const int ql = nt * 16 + quad * 4 + r;
      const float inv = 1.0f / Ls[w][ql];
      const int qrow = q0 + ql;
#pragma unroll
      for (int nd = 0; nd < 4; ++nd) {
        const int d = nd * 16 + l16;
        O[((size_t)qrow * B_DIM + b) * E_DIM + h * HD + d] = (f16_t)(oacc[nt][nd][r] * inv);
      }
    }
}

extern "C" void kernel_launch(void* const* d_in, const int* in_sizes, int n_in,
                              void* d_out, int out_size, void* d_ws, size_t ws_size,
                              hipStream_t stream) {
  const float* x     = (const float*)d_in[0];
  const float* w_in  = (const float*)d_in[1];
  const float* b_in  = (const float*)d_in[2];
  const float* w_out = (const float*)d_in[3];
  const float* b_out = (const float*)d_in[4];

  const size_t TS = (size_t)BH_DIM * L_DIM * HD;  // 8M elements per tensor
  f16_t* q16  = (f16_t*)d_ws;
  f16_t* k16  = q16 + TS;
  f16_t* v16  = k16 + TS;
  f16_t* x16  = v16 + TS;
  f16_t* wi16 = x16 + TS;
  f16_t* wo16 = wi16 + (size_t)3 * E_DIM * E_DIM;
  f16_t* ao16 = x16;   // alias: x16 dead after QKV GEMM

  // 0) fp32 -> f16 pre-convert (x, w_in, w_out)
  convert_f16<<<4096, 256, 0, stream>>>(x, w_in, w_out, x16, wi16, wo16);
  // 1) QKV projection: 256^2 lgkm-pipelined kernel, 384 wg x 512 thr
  gemm_qkv<<<384, 512, 0, stream>>>(x16, wi16, b_in, q16, k16, v16);
  // 2) attention: 128 (b,h) x 4 q-blocks of 256
  attn_f16<<<dim3(4, 128), 256, 0, stream>>>(q16, k16, v16, ao16);
  // 3) out projection: [8192,1024] x [1024,1024]^T -> fp32 d_out
  gemm_f16<1><<<dim3(8, 64), 256, 0, stream>>>(ao16, wo16, b_out, d_out, nullptr, nullptr);
}

// Round 3
// 247.972 us; speedup vs baseline: 1.1723x; 1.1723x over previous
//
#include <hip/hip_runtime.h>

// Problem constants: x [L,B,E], H heads, head dim 64.
#define L_DIM 1024
#define B_DIM 8
#define E_DIM 1024
#define H_DIM 16
#define HD 64
#define BH_DIM (B_DIM * H_DIM)  // 128

typedef float f32x4 __attribute__((ext_vector_type(4)));
typedef _Float16 f16_t;
typedef f16_t f16x4 __attribute__((ext_vector_type(4)));
typedef f16_t f16x8 __attribute__((ext_vector_type(8)));

// async global->LDS, 16 B per lane (m97 pattern): wave-uniform base + lane*16.
static __device__ __forceinline__ void gld16(const void* g, void* l) {
  __builtin_amdgcn_global_load_lds(
      (const __attribute__((address_space(1))) unsigned int*)g,
      (__attribute__((address_space(3))) unsigned int*)l, 16, 0, 0);
}

// fp32 -> f16 pre-convert of x, w_in, w_out (grid-stride over float4 units).
__global__ __launch_bounds__(256) void convert_f16(
    const float* __restrict__ x, const float* __restrict__ wi,
    const float* __restrict__ wo, f16_t* __restrict__ x16,
    f16_t* __restrict__ wi16, f16_t* __restrict__ wo16) {
  const int NX = (L_DIM * B_DIM * E_DIM) / 4;   // 2097152
  const int NWI = (3 * E_DIM * E_DIM) / 4;      // 786432
  const int NWO = (E_DIM * E_DIM) / 4;          // 262144
  const int total = NX + NWI + NWO;
  for (int i = blockIdx.x * blockDim.x + threadIdx.x; i < total;
       i += gridDim.x * blockDim.x) {
    const float4* src; f16_t* dst; int j;
    if (i < NX)            { src = (const float4*)x;  dst = x16;  j = i; }
    else if (i < NX + NWI) { src = (const float4*)wi; dst = wi16; j = i - NX; }
    else                   { src = (const float4*)wo; dst = wo16; j = i - NX - NWI; }
    const float4 v = src[j];
    f16x4 h = {(f16_t)v.x, (f16_t)v.y, (f16_t)v.z, (f16_t)v.w};
    *(f16x4*)(dst + (size_t)j * 4) = h;
  }
}

// ---------------------------------------------------------------------------
// QKV GEMM, 256x256, BK=64, 8 waves, double-buffered 128 KiB LDS.
// Round-3 change vs round-1 (which measured 74 us, MfmaUtil 26%): REMOVE the
// explicit "s_waitcnt lgkmcnt(0) + sched_barrier(0)" before the MFMA cluster.
// That drain forced ALL 6-12 ds_reads of a phase to complete before ANY MFMA
// issued, serializing the LDS window (~190-580 cyc) with the MFMA window
// (~620 cyc/CU) every phase (measured 1387 cyc/phase).  The compiler's own
// dependency tracking emits precise counted lgkmcnt(N) per fragment (m97 asm
// evidence), so the first MFMA starts as soon as its frags land and the
// remaining reads serve UNDER the MFMA cluster -- intra-phase overlap with
// zero extra registers (round-2's register double-buffer attempt spilled:
// WRITE_SIZE 52->109 MB).
//
// Schedule (unchanged from round-1, verified pass): per phase g of tile t:
// stage one half-tile (2 gld16), ds_read A-frags (4 b128; +8 B-frags at g0),
// barrier, setprio(1), 16 MFMA (compiler-inserted lgkm waits), setprio(0),
// [vmcnt(4) at g3 only -- counted, never 0 in loop], barrier.
// In-flight gld16 per thread: enter tile with 4 (B next); g0..g3 add 2 each
// -> 12 at g3; vmcnt(4) completes B(t+1)+A(t+1) (8 oldest) for tile t+1.
// Buffer safety: reads of buf d all complete before any wave passes the
// post-MFMA barrier of that phase (MFMAs consume all frags); stages into the
// other buffer region issue >=2 barriers later.  XOR swizzle (granule^=row&7)
// on both sides (pre-swizzled global src, swizzled ds_read) -- measured 0
// bank conflicts in round 1.
// ---------------------------------------------------------------------------

#define GQ_FENCE asm volatile("" ::: "memory")
#define GQ_BARRIER do { GQ_FENCE; __builtin_amdgcn_s_barrier(); GQ_FENCE; } while (0)
#define GQ_VMCNT4 asm volatile("s_waitcnt vmcnt(4)" ::: "memory")

// stage one 128x64 half-tile (16 KB) = 2 x gld16 per thread (512 threads).
#define STAGE_A(d, ht, kt) do {                                              \
    gld16(Asrc + (size_t)(ht) * (128 * 1024) + (kt) * 64,                    \
          &As[(d) * 16384 + (ht) * 8192 + tid * 8]);                         \
    gld16(Asrc + (size_t)(ht) * (128 * 1024) + 64 * 1024 + (kt) * 64,        \
          &As[(d) * 16384 + (ht) * 8192 + 4096 + tid * 8]);                  \
  } while (0)
#define STAGE_B(d, ht, kt) do {                                              \
    gld16(Bsrc + (size_t)(ht) * (128 * 1024) + (kt) * 64,                    \
          &Bs[(d) * 16384 + (ht) * 8192 + tid * 8]);                         \
    gld16(Bsrc + (size_t)(ht) * (128 * 1024) + 64 * 1024 + (kt) * 64,        \
          &Bs[(d) * 16384 + (ht) * 8192 + 4096 + tid * 8]);                  \
  } while (0)

// swizzled frag pointer: logical byte = r*128 + ks*64 + quad*16, physical
// XORs (r&7)<<4.  r always = base + l16 so r&7 == l16&7.
static __device__ __forceinline__ const f16x8* fp16frag(
    const f16_t* tile, int r, int ks, int quad, int l16) {
  const int bo = (r * 128 + ks * 64 + quad * 16) ^ ((l16 & 7) << 4);
  return (const f16x8*)((const char*)tile + bo);
}

// one phase: stage 1 half-tile, ds_read frags, barrier, 16 MFMA under
// setprio with COMPILER-scheduled lgkm waits, counted vm-wait, barrier.
#define GQ_PHASE(d, g, STAGE_STMT, ENDWAIT) do {                             \
    STAGE_STMT;                                                              \
    f16x8 af_[2][2];                                                         \
    _Pragma("unroll") for (int f_ = 0; f_ < 2; ++f_)                         \
      _Pragma("unroll") for (int ks_ = 0; ks_ < 2; ++ks_)                    \
        af_[f_][ks_] = *fp16frag(&As[(d) * 16384],                           \
            wr * 128 + ((g) * 2 + f_) * 16 + l16, ks_, quad, l16);           \
    if ((g) == 0) {                                                          \
      _Pragma("unroll") for (int c_ = 0; c_ < 4; ++c_)                       \
        _Pragma("unroll") for (int ks_ = 0; ks_ < 2; ++ks_)                  \
          bf[c_][ks_] = *fp16frag(&Bs[(d) * 16384],                          \
              wc * 64 + c_ * 16 + l16, ks_, quad, l16);                      \
    }                                                                        \
    GQ_BARRIER;                                                              \
    __builtin_amdgcn_s_setprio(1);                                           \
    _Pragma("unroll") for (int f_ = 0; f_ < 2; ++f_)                         \
      _Pragma("unroll") for (int c_ = 0; c_ < 4; ++c_)                       \
        _Pragma("unroll") for (int ks_ = 0; ks_ < 2; ++ks_)                  \
          acc[(g) * 2 + f_][c_] = __builtin_amdgcn_mfma_f32_16x16x32_f16(    \
              af_[f_][ks_], bf[c_][ks_], acc[(g) * 2 + f_][c_], 0, 0, 0);    \
    __builtin_amdgcn_s_setprio(0);                                           \
    ENDWAIT;                                                                 \
    GQ_BARRIER;                                                              \
  } while (0)

__global__ __launch_bounds__(512, 2) void gemm_qkv(
    const f16_t* __restrict__ A, const f16_t* __restrict__ B,
    const float* __restrict__ bias, f16_t* __restrict__ Oq,
    f16_t* __restrict__ Ok, f16_t* __restrict__ Ov) {
  constexpr int K = 1024;
  constexpr int NT = K / 64;  // 16 K-tiles
  __shared__ __align__(16) f16_t As[2 * 16384];  // 64 KB: dbuf x 256x64
  __shared__ __align__(16) f16_t Bs[2 * 16384];  // 64 KB

  const int tid = threadIdx.x;
  const int lane = tid & 63;
  const int w = tid >> 6;       // 0..7
  const int wr = w >> 2;        // M half
  const int wc = w & 3;         // N quarter
  const int quad = lane >> 4;
  const int l16 = lane & 15;

  // XCD-aware bijective swizzle: 384 wg = 8 XCDs x 48.
  const int bid = blockIdx.x;
  const int wg = (bid & 7) * 48 + (bid >> 3);
  const int tn = wg >> 5;       // 0..11
  const int tm = wg & 31;       // 0..31
  const int m0 = tm * 256;
  const int n0 = tn * 256;

  // staging: thread covers row srow (of a 128-row half), swizzled col block.
  const int srow = tid >> 3;
  const int scol = ((tid & 7) ^ (srow & 7)) * 8;  // pre-swizzled global col
  const f16_t* Asrc = A + (size_t)(m0 + srow) * K + scol;
  const f16_t* Bsrc = B + (size_t)(n0 + srow) * K + scol;

  f32x4 acc[8][4] = {};
  f16x8 bf[4][2];

  // Prologue: A(0), B(0), B(1); vmcnt(4) -> A(0)+B(0) done, B(1) in flight.
  STAGE_A(0, 0, 0); STAGE_A(0, 1, 0);
  STAGE_B(0, 0, 0); STAGE_B(0, 1, 0);
  STAGE_B(1, 0, 1); STAGE_B(1, 1, 1);
  GQ_VMCNT4;
  GQ_BARRIER;

  for (int it = 0; it < 8; ++it) {
    const int t1 = 2 * it + 1;
    const int ta = (2 * it + 2 < NT) ? 2 * it + 2 : NT - 1;  // clamped: keeps
    const int tb = (2 * it + 3 < NT) ? 2 * it + 3 : NT - 1;  // vmcnt counts fixed
    // tile t0 = 2*it from dbuf0
    GQ_PHASE(0, 0, STAGE_A(1, 0, t1), );
    GQ_PHASE(0, 1, STAGE_A(1, 1, t1), );
    GQ_PHASE(0, 2, STAGE_B(0, 0, ta), );
    GQ_PHASE(0, 3, STAGE_B(0, 1, ta), GQ_VMCNT4);
    // tile t1 from dbuf1
    GQ_PHASE(1, 0, STAGE_A(0, 0, ta), );
    GQ_PHASE(1, 1, STAGE_A(0, 1, ta), );
    GQ_PHASE(1, 2, STAGE_B(1, 0, tb), );
    GQ_PHASE(1, 3, STAGE_B(1, 1, tb), GQ_VMCNT4);
  }

  // Epilogue: C/D layout col=l16, row=quad*4+r.  q/k/v scatter as before.
#pragma unroll
  for (int i = 0; i < 8; ++i) {
    const int mbase = m0 + wr * 128 + i * 16 + quad * 4;
#pragma unroll
    for (int c = 0; c < 4; ++c) {
      const int n = n0 + wc * 64 + c * 16 + l16;
      const float bv = bias[n];
      const int chunk = n >> 10;      // 0=q 1=k 2=v (uniform per 16-wide frag)
      const int e = n & 1023;
      const int h = e >> 6;
      const int d = e & 63;
#pragma unroll
      for (int r = 0; r < 4; ++r) {
        const int m = mbase + r;
        const int l = m >> 3, b = m & 7;          // row m = l*B + b
        const size_t idx = ((size_t)(b * H_DIM + h) * L_DIM + l) * HD + d;
        const float val = acc[i][c][r] + bv;
        if (chunk == 0)      Oq[idx] = (f16_t)(val * 0.125f);  // 64^-0.5
        else if (chunk == 1) Ok[idx] = (f16_t)val;
        else                 Ov[idx] = (f16_t)val;
      }
    }
  }
}

// ---------------------------------------------------------------------------
// Out-proj GEMM kept on the m97 128x128 structure (N=1024 -> only 128 blocks
// at 256^2, half the GPU idle; revisit after QKV schedule is settled).
// ---------------------------------------------------------------------------
template <int MODE>
__global__ __launch_bounds__(256, 2) void gemm_f16(
    const f16_t* __restrict__ A, const f16_t* __restrict__ B,
    const float* __restrict__ bias, void* __restrict__ O0v,
    void* __restrict__ O1v, void* __restrict__ O2v) {
  constexpr int K = 1024;
  __shared__ __align__(16) f16_t As[128 * 32];
  __shared__ __align__(16) f16_t Bs[128 * 32];

  const int tid = threadIdx.x;
  const int lane = tid & 63;
  const int wave = tid >> 6;
  const int wm = (wave & 1) * 64;
  const int wn = (wave >> 1) * 64;
  const int quad = lane >> 4;
  const int l16 = lane & 15;
  const int m0 = blockIdx.y * 128;
  const int n0 = blockIdx.x * 128;

  const int cr = tid >> 2;
  const int cc = (tid & 3) * 8;

  f32x4 acc[4][4] = {};

  for (int k0 = 0; k0 < K; k0 += 32) {
    __syncthreads();
    gld16(A + (size_t)(m0 + cr) * K + k0 + cc,      As + tid * 8);
    gld16(A + (size_t)(m0 + 64 + cr) * K + k0 + cc, As + 2048 + tid * 8);
    gld16(B + (size_t)(n0 + cr) * K + k0 + cc,      Bs + tid * 8);
    gld16(B + (size_t)(n0 + 64 + cr) * K + k0 + cc, Bs + 2048 + tid * 8);
    __syncthreads();

    f16x8 af[4], bfr[4];
#pragma unroll
    for (int t = 0; t < 4; ++t) {
      af[t]  = *(const f16x8*)&As[(wm + t * 16 + l16) * 32 + quad * 8];
      bfr[t] = *(const f16x8*)&Bs[(wn + t * 16 + l16) * 32 + quad * 8];
    }
#pragma unroll
    for (int i = 0; i < 4; ++i)
#pragma unroll
      for (int j = 0; j < 4; ++j)
        acc[i][j] = __builtin_amdgcn_mfma_f32_16x16x32_f16(af[i], bfr[j], acc[i][j], 0, 0, 0);
  }

#pragma unroll
  for (int i = 0; i < 4; ++i) {
    const int mbase = m0 + wm + i * 16 + quad * 4;
#pragma unroll
    for (int j = 0; j < 4; ++j) {
      const int n = n0 + wn + j * 16 + l16;
      const float bv = bias[n];
      if (MODE == 0) {
        f16_t* O0 = (f16_t*)O0v; f16_t* O1 = (f16_t*)O1v; f16_t* O2 = (f16_t*)O2v;
        const int chunk = n >> 10;
        const int e = n & 1023;
        const int h = e >> 6;
        const int d = e & 63;
#pragma unroll
        for (int r = 0; r < 4; ++r) {
          const int m = mbase + r;
          const int l = m >> 3, b = m & 7;
          const size_t idx = ((size_t)(b * H_DIM + h) * L_DIM + l) * HD + d;
          const float val = acc[i][j][r] + bv;
          if (chunk == 0)      O0[idx] = (f16_t)(val * 0.125f);
          else if (chunk == 1) O1[idx] = (f16_t)val;
          else                 O2[idx] = (f16_t)val;
        }
      } else {
        float* O0 = (float*)O0v;
#pragma unroll
        for (int r = 0; r < 4; ++r) {
          const int m = mbase + r;
          O0[(size_t)m * E_DIM + n] = acc[i][j][r] + bv;
        }
      }
    }
  }
}

// Attention v5 (unchanged this round): all-f16, 64 q per wave, S^T = K.Q^T
// with permuted key->row mapping, in-register P, V^T staged in-kernel.
__global__ __launch_bounds__(256, 2) void attn_f16(
    const f16_t* __restrict__ Q, const f16_t* __restrict__ K,
    const f16_t* __restrict__ V, f16_t* __restrict__ O) {
  constexpr int KSTR = 70;
  __shared__ __align__(16) f16_t Ks[64 * KSTR];
  __shared__ __align__(16) f16_t Vs[64 * KSTR];
  __shared__ float Ls[4][64];

  const int tid = threadIdx.x;
  const int lane = tid & 63;
  const int w = tid >> 6;
  const int quad = lane >> 4;
  const int l16 = lane & 15;
  const int bh = blockIdx.y;
  const int q0 = blockIdx.x * 256 + w * 64;

  const f16_t* Qb = Q + (size_t)bh * L_DIM * HD;
  const f16_t* Kb = K + (size_t)bh * L_DIM * HD;
  const f16_t* Vb = V + (size_t)bh * L_DIM * HD;

  f16x8 qf[4][2];
#pragma unroll
  for (int nt = 0; nt < 4; ++nt)
#pragma unroll
    for (int kc = 0; kc < 2; ++kc)
      qf[nt][kc] = *(const f16x8*)(Qb + (size_t)(q0 + nt * 16 + l16) * HD + kc * 32 + quad * 8);

  f32x4 oacc[4][4] = {};
  float rsum[4] = {0.0f, 0.0f, 0.0f, 0.0f};

  const int sr = tid >> 3;
  const int sc8 = (tid & 7) * 8;
  const int va = tid & 31;
  const int vg = tid >> 5;
  const int rA = (l16 >> 2) * 8 + (l16 & 3);

  for (int kt = 0; kt < 16; ++kt) {
    __syncthreads();
    {
      const f16_t* kp = Kb + (size_t)(kt * 64) * HD;
#pragma unroll
      for (int rr = 0; rr < 2; ++rr) {
        const int row = sr + rr * 32;
        *(f16x8*)&Ks[row * KSTR + sc8] = *(const f16x8*)(kp + (size_t)row * HD + sc8);
      }
      const f16_t* vp = Vb + (size_t)(kt * 64 + vg * 8) * HD + 2 * va;
      unsigned int vd[8];
#pragma unroll
      for (int i = 0; i < 8; ++i) vd[i] = *(const unsigned int*)(vp + (size_t)i * HD);
      union { unsigned int u[4]; f16x8 v; } lo, hi;
#pragma unroll
      for (int i = 0; i < 4; ++i) {
        lo.u[i] = (vd[2 * i] & 0xffffu) | (vd[2 * i + 1] << 16);
        hi.u[i] = (vd[2 * i] >> 16) | (vd[2 * i + 1] & 0xffff0000u);
      }
      *(f16x8*)&Vs[(2 * va) * KSTR + vg * 8] = lo.v;
      *(f16x8*)&Vs[(2 * va + 1) * KSTR + vg * 8] = hi.v;
    }
    __syncthreads();

#pragma unroll
    for (int c = 0; c < 2; ++c) {
      f32x4 sc[2][4] = {};
#pragma unroll
      for (int h = 0; h < 2; ++h) {
        const int row = c * 32 + h * 4 + rA;
#pragma unroll
        for (int kc = 0; kc < 2; ++kc) {
          const f16x8 ka = *(const f16x8*)&Ks[row * KSTR + kc * 32 + quad * 8];
#pragma unroll
          for (int nt = 0; nt < 4; ++nt)
            sc[h][nt] = __builtin_amdgcn_mfma_f32_16x16x32_f16(ka, qf[nt][kc], sc[h][nt], 0, 0, 0);
        }
      }

      f16x8 pa[4];
#pragma unroll
      for (int nt = 0; nt < 4; ++nt)
#pragma unroll
        for (int h = 0; h < 2; ++h)
#pragma unroll
          for (int r = 0; r < 4; ++r) {
            const float e = __expf(sc[h][nt][r]);
            rsum[nt] += e;
            pa[nt][h * 4 + r] = (f16_t)e;
          }

#pragma unroll
      for (int nd = 0; nd < 4; ++nd) {
        const f16x8 vb = *(const f16x8*)&Vs[(nd * 16 + l16) * KSTR + c * 32 + quad * 8];
#pragma unroll
        for (int nt = 0; nt < 4; ++nt)
          oacc[nt][nd] = __builtin_amdgcn_mfma_f32_16x16x32_f16(pa[nt], vb, oacc[nt][nd], 0, 0, 0);
      }
    }
  }

#pragma unroll
  for (int nt = 0; nt < 4; ++nt) {
    float rs = rsum[nt];
    rs += __shfl_xor(rs, 16); rs += __shfl_xor(rs, 32);
    if (quad == 0) Ls[w][nt * 16 + l16] = rs;
  }
  asm volatile("s_waitcnt lgkmcnt(0)" ::: "memory");

  const int b = bh >> 4;
  const int h = bh & 15;
#pragma unroll
  for (int nt = 0; nt < 4; ++nt)
#pragma unroll
    for (int r = 0; r < 4; ++r) {
      const int ql = nt * 16 + quad * 4 + r;
      const float inv = 1.0f / Ls[w][ql];
      const int qrow = q0 + ql;
#pragma unroll
      for (int nd = 0; nd < 4; ++nd) {
        const int d = nd * 16 + l16;
        O[((size_t)qrow * B_DIM + b) * E_DIM + h * HD + d] = (f16_t)(oacc[nt][nd][r] * inv);
      }
    }
}

extern "C" void kernel_launch(void* const* d_in, const int* in_sizes, int n_in,
                              void* d_out, int out_size, void* d_ws, size_t ws_size,
                              hipStream_t stream) {
  const float* x     = (const float*)d_in[0];
  const float* w_in  = (const float*)d_in[1];
  const float* b_in  = (const float*)d_in[2];
  const float* w_out = (const float*)d_in[3];
  const float* b_out = (const float*)d_in[4];

  const size_t TS = (size_t)BH_DIM * L_DIM * HD;  // 8M elements per tensor
  f16_t* q16  = (f16_t*)d_ws;
  f16_t* k16  = q16 + TS;
  f16_t* v16  = k16 + TS;
  f16_t* x16  = v16 + TS;
  f16_t* wi16 = x16 + TS;
  f16_t* wo16 = wi16 + (size_t)3 * E_DIM * E_DIM;
  f16_t* ao16 = x16;   // alias: x16 dead after QKV GEMM

  // 0) fp32 -> f16 pre-convert (x, w_in, w_out)
  convert_f16<<<4096, 256, 0, stream>>>(x, w_in, w_out, x16, wi16, wo16);
  // 1) QKV projection: 256^2 8-phase kernel, compiler-scheduled lgkm waits
  gemm_qkv<<<384, 512, 0, stream>>>(x16, wi16, b_in, q16, k16, v16);
  // 2) attention: 128 (b,h) x 4 q-blocks of 256
  attn_f16<<<dim3(4, 128), 256, 0, stream>>>(q16, k16, v16, ao16);
  // 3) out projection: [8192,1024] x [1024,1024]^T -> fp32 d_out
  gemm_f16<1><<<dim3(8, 64), 256, 0, stream>>>(ao16, wo16, b_out, d_out, nullptr, nullptr);
}

// Round 4
// 243.910 us; speedup vs baseline: 1.1918x; 1.0167x over previous
//
#include <hip/hip_runtime.h>

// Problem constants: x [L,B,E], H heads, head dim 64.
#define L_DIM 1024
#define B_DIM 8
#define E_DIM 1024
#define H_DIM 16
#define HD 64
#define BH_DIM (B_DIM * H_DIM)  // 128

typedef float f32x4 __attribute__((ext_vector_type(4)));
typedef _Float16 f16_t;
typedef f16_t f16x4 __attribute__((ext_vector_type(4)));
typedef f16_t f16x8 __attribute__((ext_vector_type(8)));

// async global->LDS, 16 B per lane (m97 pattern): wave-uniform base + lane*16.
static __device__ __forceinline__ void gld16(const void* g, void* l) {
  __builtin_amdgcn_global_load_lds(
      (const __attribute__((address_space(1))) unsigned int*)g,
      (__attribute__((address_space(3))) unsigned int*)l, 16, 0, 0);
}

// fp32 -> f16 pre-convert of x, w_in, w_out (grid-stride over float4 units).
__global__ __launch_bounds__(256) void convert_f16(
    const float* __restrict__ x, const float* __restrict__ wi,
    const float* __restrict__ wo, f16_t* __restrict__ x16,
    f16_t* __restrict__ wi16, f16_t* __restrict__ wo16) {
  const int NX = (L_DIM * B_DIM * E_DIM) / 4;   // 2097152
  const int NWI = (3 * E_DIM * E_DIM) / 4;      // 786432
  const int NWO = (E_DIM * E_DIM) / 4;          // 262144
  const int total = NX + NWI + NWO;
  for (int i = blockIdx.x * blockDim.x + threadIdx.x; i < total;
       i += gridDim.x * blockDim.x) {
    const float4* src; f16_t* dst; int j;
    if (i < NX)            { src = (const float4*)x;  dst = x16;  j = i; }
    else if (i < NX + NWI) { src = (const float4*)wi; dst = wi16; j = i - NX; }
    else                   { src = (const float4*)wo; dst = wo16; j = i - NX - NWI; }
    const float4 v = src[j];
    f16x4 h = {(f16_t)v.x, (f16_t)v.y, (f16_t)v.z, (f16_t)v.w};
    *(f16x4*)(dst + (size_t)j * 4) = h;
  }
}

// ---------------------------------------------------------------------------
// QKV GEMM, 256x256, BK=64, 8 waves, double-buffered 128 KiB LDS.
// Round-4 change vs round-3 (77.9 us, MfmaUtil 26%): move the per-phase
// gld16 STAGE from before the ds_reads to AFTER the MFMA cluster.
//
// Theory: global_load_lds writes LDS invisibly; the backend must order any
// ds_read against pending LDS-DMA writes it cannot disambiguate (same
// __shared__ arrays), so it inserts a hidden vmcnt wait before each phase's
// ds_reads.  With the stage issued immediately before the reads (rounds
// 1/3), that wait exposes ~900 cyc of HBM latency EVERY phase — the ~650
// unexplained cyc/phase (measured 1462 vs ~800 modeled).  With the stage
// moved after the MFMAs, the nearest hazarding DMA at any ds_read is >=1
// full phase old (~1400 cyc > 900 cyc HBM latency), so the hazard wait is
// ~free under both precise and conservative insertion.
//
// vmcnt counting unchanged (same issue order): per-thread loads in flight:
// prologue 12, vmcnt(4) -> B(1):4.  Tile-half: g0 +2, g1 +2, g2 +2, g3 +2
// -> 12, vmcnt(4) retires the 8 oldest (prev B + this A), leaves 4 (next B).
// WAR safety: stage into buf d' now sits one barrier FURTHER after the last
// reads of d' than in round 3 (which passed).  Clamped tail stages rewrite
// identical bytes (benign, unchanged from rounds 1/3).
// ---------------------------------------------------------------------------

#define GQ_FENCE asm volatile("" ::: "memory")
#define GQ_BARRIER do { GQ_FENCE; __builtin_amdgcn_s_barrier(); GQ_FENCE; } while (0)
#define GQ_VMCNT4 asm volatile("s_waitcnt vmcnt(4)" ::: "memory")

// stage one 128x64 half-tile (16 KB) = 2 x gld16 per thread (512 threads).
#define STAGE_A(d, ht, kt) do {                                              \
    gld16(Asrc + (size_t)(ht) * (128 * 1024) + (kt) * 64,                    \
          &As[(d) * 16384 + (ht) * 8192 + tid * 8]);                         \
    gld16(Asrc + (size_t)(ht) * (128 * 1024) + 64 * 1024 + (kt) * 64,        \
          &As[(d) * 16384 + (ht) * 8192 + 4096 + tid * 8]);                  \
  } while (0)
#define STAGE_B(d, ht, kt) do {                                              \
    gld16(Bsrc + (size_t)(ht) * (128 * 1024) + (kt) * 64,                    \
          &Bs[(d) * 16384 + (ht) * 8192 + tid * 8]);                         \
    gld16(Bsrc + (size_t)(ht) * (128 * 1024) + 64 * 1024 + (kt) * 64,        \
          &Bs[(d) * 16384 + (ht) * 8192 + 4096 + tid * 8]);                  \
  } while (0)

// swizzled frag pointer: logical byte = r*128 + ks*64 + quad*16, physical
// XORs (r&7)<<4.  r always = base + l16 so r&7 == l16&7.  (bank conflicts
// measured 0 with this in rounds 1 and 3.)
static __device__ __forceinline__ const f16x8* fp16frag(
    const f16_t* tile, int r, int ks, int quad, int l16) {
  const int bo = (r * 128 + ks * 64 + quad * 16) ^ ((l16 & 7) << 4);
  return (const f16x8*)((const char*)tile + bo);
}

// one phase: ds_read frags, barrier, 16 MFMA under setprio (compiler-
// scheduled lgkm waits), THEN stage 1 half-tile, counted vm-wait, barrier.
#define GQ_PHASE(d, g, STAGE_STMT, ENDWAIT) do {                             \
    f16x8 af_[2][2];                                                         \
    _Pragma("unroll") for (int f_ = 0; f_ < 2; ++f_)                         \
      _Pragma("unroll") for (int ks_ = 0; ks_ < 2; ++ks_)                    \
        af_[f_][ks_] = *fp16frag(&As[(d) * 16384],                           \
            wr * 128 + ((g) * 2 + f_) * 16 + l16, ks_, quad, l16);           \
    if ((g) == 0) {                                                          \
      _Pragma("unroll") for (int c_ = 0; c_ < 4; ++c_)                       \
        _Pragma("unroll") for (int ks_ = 0; ks_ < 2; ++ks_)                  \
          bf[c_][ks_] = *fp16frag(&Bs[(d) * 16384],                          \
              wc * 64 + c_ * 16 + l16, ks_, quad, l16);                      \
    }                                                                        \
    GQ_BARRIER;                                                              \
    __builtin_amdgcn_s_setprio(1);                                           \
    _Pragma("unroll") for (int f_ = 0; f_ < 2; ++f_)                         \
      _Pragma("unroll") for (int c_ = 0; c_ < 4; ++c_)                       \
        _Pragma("unroll") for (int ks_ = 0; ks_ < 2; ++ks_)                  \
          acc[(g) * 2 + f_][c_] = __builtin_amdgcn_mfma_f32_16x16x32_f16(    \
              af_[f_][ks_], bf[c_][ks_], acc[(g) * 2 + f_][c_], 0, 0, 0);    \
    __builtin_amdgcn_s_setprio(0);                                           \
    STAGE_STMT;                                                              \
    ENDWAIT;                                                                 \
    GQ_BARRIER;                                                              \
  } while (0)

__global__ __launch_bounds__(512, 2) void gemm_qkv(
    const f16_t* __restrict__ A, const f16_t* __restrict__ B,
    const float* __restrict__ bias, f16_t* __restrict__ Oq,
    f16_t* __restrict__ Ok, f16_t* __restrict__ Ov) {
  constexpr int K = 1024;
  constexpr int NT = K / 64;  // 16 K-tiles
  __shared__ __align__(16) f16_t As[2 * 16384];  // 64 KB: dbuf x 256x64
  __shared__ __align__(16) f16_t Bs[2 * 16384];  // 64 KB

  const int tid = threadIdx.x;
  const int lane = tid & 63;
  const int w = tid >> 6;       // 0..7
  const int wr = w >> 2;        // M half
  const int wc = w & 3;         // N quarter
  const int quad = lane >> 4;
  const int l16 = lane & 15;

  // XCD-aware bijective swizzle: 384 wg = 8 XCDs x 48.
  const int bid = blockIdx.x;
  const int wg = (bid & 7) * 48 + (bid >> 3);
  const int tn = wg >> 5;       // 0..11
  const int tm = wg & 31;       // 0..31
  const int m0 = tm * 256;
  const int n0 = tn * 256;

  // staging: thread covers row srow (of a 128-row half), swizzled col block.
  const int srow = tid >> 3;
  const int scol = ((tid & 7) ^ (srow & 7)) * 8;  // pre-swizzled global col
  const f16_t* Asrc = A + (size_t)(m0 + srow) * K + scol;
  const f16_t* Bsrc = B + (size_t)(n0 + srow) * K + scol;

  f32x4 acc[8][4] = {};
  f16x8 bf[4][2];

  // Prologue: A(0), B(0), B(1); vmcnt(4) -> A(0)+B(0) done, B(1) in flight.
  STAGE_A(0, 0, 0); STAGE_A(0, 1, 0);
  STAGE_B(0, 0, 0); STAGE_B(0, 1, 0);
  STAGE_B(1, 0, 1); STAGE_B(1, 1, 1);
  GQ_VMCNT4;
  GQ_BARRIER;

  for (int it = 0; it < 8; ++it) {
    const int t1 = 2 * it + 1;
    const int ta = (2 * it + 2 < NT) ? 2 * it + 2 : NT - 1;  // clamped: keeps
    const int tb = (2 * it + 3 < NT) ? 2 * it + 3 : NT - 1;  // vmcnt counts fixed
    // tile t0 = 2*it from dbuf0
    GQ_PHASE(0, 0, STAGE_A(1, 0, t1), );
    GQ_PHASE(0, 1, STAGE_A(1, 1, t1), );
    GQ_PHASE(0, 2, STAGE_B(0, 0, ta), );
    GQ_PHASE(0, 3, STAGE_B(0, 1, ta), GQ_VMCNT4);
    // tile t1 from dbuf1
    GQ_PHASE(1, 0, STAGE_A(0, 0, ta), );
    GQ_PHASE(1, 1, STAGE_A(0, 1, ta), );
    GQ_PHASE(1, 2, STAGE_B(1, 0, tb), );
    GQ_PHASE(1, 3, STAGE_B(1, 1, tb), GQ_VMCNT4);
  }

  // Epilogue: C/D layout col=l16, row=quad*4+r.  q/k/v scatter as before.
#pragma unroll
  for (int i = 0; i < 8; ++i) {
    const int mbase = m0 + wr * 128 + i * 16 + quad * 4;
#pragma unroll
    for (int c = 0; c < 4; ++c) {
      const int n = n0 + wc * 64 + c * 16 + l16;
      const float bv = bias[n];
      const int chunk = n >> 10;      // 0=q 1=k 2=v (uniform per 16-wide frag)
      const int e = n & 1023;
      const int h = e >> 6;
      const int d = e & 63;
#pragma unroll
      for (int r = 0; r < 4; ++r) {
        const int m = mbase + r;
        const int l = m >> 3, b = m & 7;          // row m = l*B + b
        const size_t idx = ((size_t)(b * H_DIM + h) * L_DIM + l) * HD + d;
        const float val = acc[i][c][r] + bv;
        if (chunk == 0)      Oq[idx] = (f16_t)(val * 0.125f);  // 64^-0.5
        else if (chunk == 1) Ok[idx] = (f16_t)val;
        else                 Ov[idx] = (f16_t)val;
      }
    }
  }
}

// ---------------------------------------------------------------------------
// Out-proj GEMM kept on the m97 128x128 structure (N=1024 -> only 128 blocks
// at 256^2, half the GPU idle; revisit after QKV schedule is settled).
// ---------------------------------------------------------------------------
template <int MODE>
__global__ __launch_bounds__(256, 2) void gemm_f16(
    const f16_t* __restrict__ A, const f16_t* __restrict__ B,
    const float* __restrict__ bias, void* __restrict__ O0v,
    void* __restrict__ O1v, void* __restrict__ O2v) {
  constexpr int K = 1024;
  __shared__ __align__(16) f16_t As[128 * 32];
  __shared__ __align__(16) f16_t Bs[128 * 32];

  const int tid = threadIdx.x;
  const int lane = tid & 63;
  const int wave = tid >> 6;
  const int wm = (wave & 1) * 64;
  const int wn = (wave >> 1) * 64;
  const int quad = lane >> 4;
  const int l16 = lane & 15;
  const int m0 = blockIdx.y * 128;
  const int n0 = blockIdx.x * 128;

  const int cr = tid >> 2;
  const int cc = (tid & 3) * 8;

  f32x4 acc[4][4] = {};

  for (int k0 = 0; k0 < K; k0 += 32) {
    __syncthreads();
    gld16(A + (size_t)(m0 + cr) * K + k0 + cc,      As + tid * 8);
    gld16(A + (size_t)(m0 + 64 + cr) * K + k0 + cc, As + 2048 + tid * 8);
    gld16(B + (size_t)(n0 + cr) * K + k0 + cc,      Bs + tid * 8);
    gld16(B + (size_t)(n0 + 64 + cr) * K + k0 + cc, Bs + 2048 + tid * 8);
    __syncthreads();

    f16x8 af[4], bfr[4];
#pragma unroll
    for (int t = 0; t < 4; ++t) {
      af[t]  = *(const f16x8*)&As[(wm + t * 16 + l16) * 32 + quad * 8];
      bfr[t] = *(const f16x8*)&Bs[(wn + t * 16 + l16) * 32 + quad * 8];
    }
#pragma unroll
    for (int i = 0; i < 4; ++i)
#pragma unroll
      for (int j = 0; j < 4; ++j)
        acc[i][j] = __builtin_amdgcn_mfma_f32_16x16x32_f16(af[i], bfr[j], acc[i][j], 0, 0, 0);
  }

#pragma unroll
  for (int i = 0; i < 4; ++i) {
    const int mbase = m0 + wm + i * 16 + quad * 4;
#pragma unroll
    for (int j = 0; j < 4; ++j) {
      const int n = n0 + wn + j * 16 + l16;
      const float bv = bias[n];
      if (MODE == 0) {
        f16_t* O0 = (f16_t*)O0v; f16_t* O1 = (f16_t*)O1v; f16_t* O2 = (f16_t*)O2v;
        const int chunk = n >> 10;
        const int e = n & 1023;
        const int h = e >> 6;
        const int d = e & 63;
#pragma unroll
        for (int r = 0; r < 4; ++r) {
          const int m = mbase + r;
          const int l = m >> 3, b = m & 7;
          const size_t idx = ((size_t)(b * H_DIM + h) * L_DIM + l) * HD + d;
          const float val = acc[i][j][r] + bv;
          if (chunk == 0)      O0[idx] = (f16_t)(val * 0.125f);
          else if (chunk == 1) O1[idx] = (f16_t)val;
          else                 O2[idx] = (f16_t)val;
        }
      } else {
        float* O0 = (float*)O0v;
#pragma unroll
        for (int r = 0; r < 4; ++r) {
          const int m = mbase + r;
          O0[(size_t)m * E_DIM + n] = acc[i][j][r] + bv;
        }
      }
    }
  }
}

// Attention v5 (unchanged this round): all-f16, 64 q per wave, S^T = K.Q^T
// with permuted key->row mapping, in-register P, V^T staged in-kernel.
__global__ __launch_bounds__(256, 2) void attn_f16(
    const f16_t* __restrict__ Q, const f16_t* __restrict__ K,
    const f16_t* __restrict__ V, f16_t* __restrict__ O) {
  constexpr int KSTR = 70;
  __shared__ __align__(16) f16_t Ks[64 * KSTR];
  __shared__ __align__(16) f16_t Vs[64 * KSTR];
  __shared__ float Ls[4][64];

  const int tid = threadIdx.x;
  const int lane = tid & 63;
  const int w = tid >> 6;
  const int quad = lane >> 4;
  const int l16 = lane & 15;
  const int bh = blockIdx.y;
  const int q0 = blockIdx.x * 256 + w * 64;

  const f16_t* Qb = Q + (size_t)bh * L_DIM * HD;
  const f16_t* Kb = K + (size_t)bh * L_DIM * HD;
  const f16_t* Vb = V + (size_t)bh * L_DIM * HD;

  f16x8 qf[4][2];
#pragma unroll
  for (int nt = 0; nt < 4; ++nt)
#pragma unroll
    for (int kc = 0; kc < 2; ++kc)
      qf[nt][kc] = *(const f16x8*)(Qb + (size_t)(q0 + nt * 16 + l16) * HD + kc * 32 + quad * 8);

  f32x4 oacc[4][4] = {};
  float rsum[4] = {0.0f, 0.0f, 0.0f, 0.0f};

  const int sr = tid >> 3;
  const int sc8 = (tid & 7) * 8;
  const int va = tid & 31;
  const int vg = tid >> 5;
  const int rA = (l16 >> 2) * 8 + (l16 & 3);

  for (int kt = 0; kt < 16; ++kt) {
    __syncthreads();
    {
      const f16_t* kp = Kb + (size_t)(kt * 64) * HD;
#pragma unroll
      for (int rr = 0; rr < 2; ++rr) {
        const int row = sr + rr * 32;
        *(f16x8*)&Ks[row * KSTR + sc8] = *(const f16x8*)(kp + (size_t)row * HD + sc8);
      }
      const f16_t* vp = Vb + (size_t)(kt * 64 + vg * 8) * HD + 2 * va;
      unsigned int vd[8];
#pragma unroll
      for (int i = 0; i < 8; ++i) vd[i] = *(const unsigned int*)(vp + (size_t)i * HD);
      union { unsigned int u[4]; f16x8 v; } lo, hi;
#pragma unroll
      for (int i = 0; i < 4; ++i) {
        lo.u[i] = (vd[2 * i] & 0xffffu) | (vd[2 * i + 1] << 16);
        hi.u[i] = (vd[2 * i] >> 16) | (vd[2 * i + 1] & 0xffff0000u);
      }
      *(f16x8*)&Vs[(2 * va) * KSTR + vg * 8] = lo.v;
      *(f16x8*)&Vs[(2 * va + 1) * KSTR + vg * 8] = hi.v;
    }
    __syncthreads();

#pragma unroll
    for (int c = 0; c < 2; ++c) {
      f32x4 sc[2][4] = {};
#pragma unroll
      for (int h = 0; h < 2; ++h) {
        const int row = c * 32 + h * 4 + rA;
#pragma unroll
        for (int kc = 0; kc < 2; ++kc) {
          const f16x8 ka = *(const f16x8*)&Ks[row * KSTR + kc * 32 + quad * 8];
#pragma unroll
          for (int nt = 0; nt < 4; ++nt)
            sc[h][nt] = __builtin_amdgcn_mfma_f32_16x16x32_f16(ka, qf[nt][kc], sc[h][nt], 0, 0, 0);
        }
      }

      f16x8 pa[4];
#pragma unroll
      for (int nt = 0; nt < 4; ++nt)
#pragma unroll
        for (int h = 0; h < 2; ++h)
#pragma unroll
          for (int r = 0; r < 4; ++r) {
            const float e = __expf(sc[h][nt][r]);
            rsum[nt] += e;
            pa[nt][h * 4 + r] = (f16_t)e;
          }

#pragma unroll
      for (int nd = 0; nd < 4; ++nd) {
        const f16x8 vb = *(const f16x8*)&Vs[(nd * 16 + l16) * KSTR + c * 32 + quad * 8];
#pragma unroll
        for (int nt = 0; nt < 4; ++nt)
          oacc[nt][nd] = __builtin_amdgcn_mfma_f32_16x16x32_f16(pa[nt], vb, oacc[nt][nd], 0, 0, 0);
      }
    }
  }

#pragma unroll
  for (int nt = 0; nt < 4; ++nt) {
    float rs = rsum[nt];
    rs += __shfl_xor(rs, 16); rs += __shfl_xor(rs, 32);
    if (quad == 0) Ls[w][nt * 16 + l16] = rs;
  }
  asm volatile("s_waitcnt lgkmcnt(0)" ::: "memory");

  const int b = bh >> 4;
  const int h = bh & 15;
#pragma unroll
  for (int nt = 0; nt < 4; ++nt)
#pragma unroll
    for (int r = 0; r < 4; ++r) {
      const int ql = nt * 16 + quad * 4 + r;
      const float inv = 1.0f / Ls[w][ql];
      const int qrow = q0 + ql;
#pragma unroll
      for (int nd = 0; nd < 4; ++nd) {
        const int d = nd * 16 + l16;
        O[((size_t)qrow * B_DIM + b) * E_DIM + h * HD + d] = (f16_t)(oacc[nt][nd][r] * inv);
      }
    }
}

extern "C" void kernel_launch(void* const* d_in, const int* in_sizes, int n_in,
                              void* d_out, int out_size, void* d_ws, size_t ws_size,
                              hipStream_t stream) {
  const float* x     = (const float*)d_in[0];
  const float* w_in  = (const float*)d_in[1];
  const float* b_in  = (const float*)d_in[2];
  const float* w_out = (const float*)d_in[3];
  const float* b_out = (const float*)d_in[4];

  const size_t TS = (size_t)BH_DIM * L_DIM * HD;  // 8M elements per tensor
  f16_t* q16  = (f16_t*)d_ws;
  f16_t* k16  = q16 + TS;
  f16_t* v16  = k16 + TS;
  f16_t* x16  = v16 + TS;
  f16_t* wi16 = x16 + TS;
  f16_t* wo16 = wi16 + (size_t)3 * E_DIM * E_DIM;
  f16_t* ao16 = x16;   // alias: x16 dead after QKV GEMM

  // 0) fp32 -> f16 pre-convert (x, w_in, w_out)
  convert_f16<<<4096, 256, 0, stream>>>(x, w_in, w_out, x16, wi16, wo16);
  // 1) QKV projection: 256^2 8-phase kernel, stage-after-MFMA ordering
  gemm_qkv<<<384, 512, 0, stream>>>(x16, wi16, b_in, q16, k16, v16);
  // 2) attention: 128 (b,h) x 4 q-blocks of 256
  attn_f16<<<dim3(4, 128), 256, 0, stream>>>(q16, k16, v16, ao16);
  // 3) out projection: [8192,1024] x [1024,1024]^T -> fp32 d_out
  gemm_f16<1><<<dim3(8, 64), 256, 0, stream>>>(ao16, wo16, b_out, d_out, nullptr, nullptr);
}

// Round 5
// 226.650 us; speedup vs baseline: 1.2826x; 1.0762x over previous
//
#include <hip/hip_runtime.h>

// Problem constants: x [L,B,E], H heads, head dim 64.
#define L_DIM 1024
#define B_DIM 8
#define E_DIM 1024
#define H_DIM 16
#define HD 64
#define BH_DIM (B_DIM * H_DIM)  // 128

typedef float f32x4 __attribute__((ext_vector_type(4)));
typedef _Float16 f16_t;
typedef f16_t f16x4 __attribute__((ext_vector_type(4)));
typedef f16_t f16x8 __attribute__((ext_vector_type(8)));

// async global->LDS, 16 B per lane (m97 pattern): wave-uniform base + lane*16.
static __device__ __forceinline__ void gld16(const void* g, void* l) {
  __builtin_amdgcn_global_load_lds(
      (const __attribute__((address_space(1))) unsigned int*)g,
      (__attribute__((address_space(3))) unsigned int*)l, 16, 0, 0);
}

// fp32 -> f16 pre-convert of x, w_in, w_out (grid-stride over float4 units).
__global__ __launch_bounds__(256) void convert_f16(
    const float* __restrict__ x, const float* __restrict__ wi,
    const float* __restrict__ wo, f16_t* __restrict__ x16,
    f16_t* __restrict__ wi16, f16_t* __restrict__ wo16) {
  const int NX = (L_DIM * B_DIM * E_DIM) / 4;   // 2097152
  const int NWI = (3 * E_DIM * E_DIM) / 4;      // 786432
  const int NWO = (E_DIM * E_DIM) / 4;          // 262144
  const int total = NX + NWI + NWO;
  for (int i = blockIdx.x * blockDim.x + threadIdx.x; i < total;
       i += gridDim.x * blockDim.x) {
    const float4* src; f16_t* dst; int j;
    if (i < NX)            { src = (const float4*)x;  dst = x16;  j = i; }
    else if (i < NX + NWI) { src = (const float4*)wi; dst = wi16; j = i - NX; }
    else                   { src = (const float4*)wo; dst = wo16; j = i - NX - NWI; }
    const float4 v = src[j];
    f16x4 h = {(f16_t)v.x, (f16_t)v.y, (f16_t)v.z, (f16_t)v.w};
    *(f16x4*)(dst + (size_t)j * 4) = h;
  }
}

// ---------------------------------------------------------------------------
// QKV GEMM, round-5 restructure: 128x128 tile, BK=64, double-buffered 64 KiB
// LDS -> TWO blocks per CU.  Rounds 1-4 showed the 256^2 1-block/CU schedule
// is barrier-lockstep-serialized (LDS window + MFMA window alternate, 1462
// cyc/phase) regardless of intra-block wait discipline.  The proven fix is
// m97's: cross-BLOCK overlap (m114: MFMA and LDS pipes co-schedule across
// waves of different blocks) -- block A's MFMA window hides block B's LDS
// window with zero scheduling cleverness.  Also fixes grid quantization:
// 1536 wg = exactly 3 rounds of 512 block-slots (vs 384/256 = 1.5 rounds,
// a hard 0.75x).
//
// Per tile t (fully unrolled, buffers ping-pong d = t&1):
//   vmcnt(8)    -- waits ONLY loads issued >=2 tiles ago (never stalls,
//                  never 0 in the loop: T4 done with 2 buffers)
//   barrier     -- publish all waves' stage(t) (vmcnt is per-wave!)
//   ds_read 16 b128 (swizzled, 0-conflict pattern from rounds 1-4)
//   setprio(1); 32 MFMA (compiler-counted lgkm waits); setprio(0)
//   barrier     -- all reads of buf d retired across waves
//   STAGE(t+2 -> buf d)  -- 8 gld16 into the buffer just consumed
// Prologue: STAGE(0->b0), STAGE(1->b1).  Tail stages clamp to kt=15 and
// write dead buffers (uniform vmcnt counts; harmless rewrites).
// WAR safety: stage into buf d is issued after the post-MFMA barrier, so
// every wave's reads of buf d have retired; the DMA writes land during
// t+1 and are published by t+2's vmcnt(8)+barrier.
// ---------------------------------------------------------------------------

#define GQ_FENCE asm volatile("" ::: "memory")
#define GQ_BARRIER do { GQ_FENCE; __builtin_amdgcn_s_barrier(); GQ_FENCE; } while (0)
#define VMW(n) asm volatile("s_waitcnt vmcnt(" #n ")" ::: "memory")

// swizzled frag pointer: logical byte = r*128 + ks*64 + quad*16, physical
// XORs (r&7)<<4.  r always = base + l16 so r&7 == l16&7.  Row stride is
// 128 B (64 f16) -- same geometry as rounds 1-4 (measured 0 conflicts).
static __device__ __forceinline__ const f16x8* fp16frag(
    const f16_t* tile, int r, int ks, int quad, int l16) {
  const int bo = (r * 128 + ks * 64 + quad * 16) ^ ((l16 & 7) << 4);
  return (const f16x8*)((const char*)tile + bo);
}

__global__ __launch_bounds__(256, 2) void gemm_qkv(
    const f16_t* __restrict__ A, const f16_t* __restrict__ B,
    const float* __restrict__ bias, f16_t* __restrict__ Oq,
    f16_t* __restrict__ Ok, f16_t* __restrict__ Ov) {
  constexpr int K = 1024;
  __shared__ __align__(16) f16_t As[2 * 8192];  // 32 KB: dbuf x 128x64
  __shared__ __align__(16) f16_t Bs[2 * 8192];  // 32 KB

  const int tid = threadIdx.x;
  const int lane = tid & 63;
  const int w = tid >> 6;        // 0..3
  const int wm = (w & 1) * 64;
  const int wn = (w >> 1) * 64;
  const int quad = lane >> 4;
  const int l16 = lane & 15;

  // XCD swizzle: 1536 wg = 8 XCDs x 192.  Per XCD: tm in [8x, 8x+8)
  // (A working set 2 MB, L2-resident), tn sweeps slowly (B slab 0.25 MB
  // shared by 8 consecutive blocks).
  const int bid = blockIdx.x;
  const int xcd = bid & 7;
  const int idx = bid >> 3;          // 0..191
  const int tm = xcd * 8 + (idx & 7);  // 0..63
  const int tn = idx >> 3;             // 0..23
  const int m0 = tm * 128;
  const int n0 = tn * 128;

  // Staging: 4 sweeps of 32 rows per 128x64 tile half; thread covers row
  // r8 (within sweep), pre-swizzled granule gsw (row&7 == r8&7 every sweep).
  const int r8 = tid >> 3;                    // 0..31
  const int gsw = (tid & 7) ^ (r8 & 7);
  const f16_t* Abase = A + (size_t)(m0 + r8) * K + gsw * 8;
  const f16_t* Bbase = B + (size_t)(n0 + r8) * K + gsw * 8;

#define STAGE(kt, d) do {                                                    \
    _Pragma("unroll") for (int s_ = 0; s_ < 4; ++s_)                         \
      gld16(Abase + (size_t)s_ * 32 * K + (kt) * 64,                         \
            &As[(d) * 8192 + s_ * 2048 + tid * 8]);                          \
    _Pragma("unroll") for (int s_ = 0; s_ < 4; ++s_)                         \
      gld16(Bbase + (size_t)s_ * 32 * K + (kt) * 64,                         \
            &Bs[(d) * 8192 + s_ * 2048 + tid * 8]);                          \
  } while (0)

  f32x4 acc[4][4] = {};

  // Prologue: 2-tile-deep prefetch (16 loads in flight per wave).
  STAGE(0, 0);
  STAGE(1, 1);

#pragma unroll
  for (int t = 0; t < 16; ++t) {
    const int d = t & 1;
    VMW(8);        // drains stage(t) (issued >=2 tiles ago); keeps stage(t+1)
    GQ_BARRIER;    // publish stage(t) across waves

    f16x8 af[4][2], bf[4][2];
#pragma unroll
    for (int i = 0; i < 4; ++i)
#pragma unroll
      for (int ks = 0; ks < 2; ++ks) {
        af[i][ks] = *fp16frag(&As[d * 8192], wm + i * 16 + l16, ks, quad, l16);
        bf[i][ks] = *fp16frag(&Bs[d * 8192], wn + i * 16 + l16, ks, quad, l16);
      }

    __builtin_amdgcn_s_setprio(1);
#pragma unroll
    for (int i = 0; i < 4; ++i)
#pragma unroll
      for (int j = 0; j < 4; ++j)
#pragma unroll
        for (int ks = 0; ks < 2; ++ks)
          acc[i][j] = __builtin_amdgcn_mfma_f32_16x16x32_f16(
              af[i][ks], bf[j][ks], acc[i][j], 0, 0, 0);
    __builtin_amdgcn_s_setprio(0);

    GQ_BARRIER;    // all waves' reads of buf d retired -> safe to overwrite
    const int kt2 = (t + 2 < 16) ? t + 2 : 15;  // clamped tail: dead rewrite,
    STAGE(kt2, d);                              // keeps vmcnt counts uniform
  }

  // Epilogue: C/D layout col=l16, row=quad*4+r.  q/k/v scatter.
#pragma unroll
  for (int i = 0; i < 4; ++i) {
    const int mbase = m0 + wm + i * 16 + quad * 4;
#pragma unroll
    for (int c = 0; c < 4; ++c) {
      const int n = n0 + wn + c * 16 + l16;
      const float bv = bias[n];
      const int chunk = n >> 10;      // 0=q 1=k 2=v (uniform per 16-wide frag)
      const int e = n & 1023;
      const int h = e >> 6;
      const int dd = e & 63;
#pragma unroll
      for (int r = 0; r < 4; ++r) {
        const int m = mbase + r;
        const int l = m >> 3, b = m & 7;          // row m = l*B + b
        const size_t idxo = ((size_t)(b * H_DIM + h) * L_DIM + l) * HD + dd;
        const float val = acc[i][c][r] + bv;
        if (chunk == 0)      Oq[idxo] = (f16_t)(val * 0.125f);  // 64^-0.5
        else if (chunk == 1) Ok[idxo] = (f16_t)val;
        else                 Ov[idxo] = (f16_t)val;
      }
    }
  }
#undef STAGE
}

// ---------------------------------------------------------------------------
// Out-proj GEMM kept on the m97 128x128 structure (unchanged this round for
// isolation; upgrade to the new template next round if QKV confirms).
// ---------------------------------------------------------------------------
template <int MODE>
__global__ __launch_bounds__(256, 2) void gemm_f16(
    const f16_t* __restrict__ A, const f16_t* __restrict__ B,
    const float* __restrict__ bias, void* __restrict__ O0v,
    void* __restrict__ O1v, void* __restrict__ O2v) {
  constexpr int K = 1024;
  __shared__ __align__(16) f16_t As[128 * 32];
  __shared__ __align__(16) f16_t Bs[128 * 32];

  const int tid = threadIdx.x;
  const int lane = tid & 63;
  const int wave = tid >> 6;
  const int wm = (wave & 1) * 64;
  const int wn = (wave >> 1) * 64;
  const int quad = lane >> 4;
  const int l16 = lane & 15;
  const int m0 = blockIdx.y * 128;
  const int n0 = blockIdx.x * 128;

  const int cr = tid >> 2;
  const int cc = (tid & 3) * 8;

  f32x4 acc[4][4] = {};

  for (int k0 = 0; k0 < K; k0 += 32) {
    __syncthreads();
    gld16(A + (size_t)(m0 + cr) * K + k0 + cc,      As + tid * 8);
    gld16(A + (size_t)(m0 + 64 + cr) * K + k0 + cc, As + 2048 + tid * 8);
    gld16(B + (size_t)(n0 + cr) * K + k0 + cc,      Bs + tid * 8);
    gld16(B + (size_t)(n0 + 64 + cr) * K + k0 + cc, Bs + 2048 + tid * 8);
    __syncthreads();

    f16x8 af[4], bfr[4];
#pragma unroll
    for (int t = 0; t < 4; ++t) {
      af[t]  = *(const f16x8*)&As[(wm + t * 16 + l16) * 32 + quad * 8];
      bfr[t] = *(const f16x8*)&Bs[(wn + t * 16 + l16) * 32 + quad * 8];
    }
#pragma unroll
    for (int i = 0; i < 4; ++i)
#pragma unroll
      for (int j = 0; j < 4; ++j)
        acc[i][j] = __builtin_amdgcn_mfma_f32_16x16x32_f16(af[i], bfr[j], acc[i][j], 0, 0, 0);
  }

#pragma unroll
  for (int i = 0; i < 4; ++i) {
    const int mbase = m0 + wm + i * 16 + quad * 4;
#pragma unroll
    for (int j = 0; j < 4; ++j) {
      const int n = n0 + wn + j * 16 + l16;
      const float bv = bias[n];
      if (MODE == 0) {
        f16_t* O0 = (f16_t*)O0v; f16_t* O1 = (f16_t*)O1v; f16_t* O2 = (f16_t*)O2v;
        const int chunk = n >> 10;
        const int e = n & 1023;
        const int h = e >> 6;
        const int d = e & 63;
#pragma unroll
        for (int r = 0; r < 4; ++r) {
          const int m = mbase + r;
          const int l = m >> 3, b = m & 7;
          const size_t idx = ((size_t)(b * H_DIM + h) * L_DIM + l) * HD + d;
          const float val = acc[i][j][r] + bv;
          if (chunk == 0)      O0[idx] = (f16_t)(val * 0.125f);
          else if (chunk == 1) O1[idx] = (f16_t)val;
          else                 O2[idx] = (f16_t)val;
        }
      } else {
        float* O0 = (float*)O0v;
#pragma unroll
        for (int r = 0; r < 4; ++r) {
          const int m = mbase + r;
          O0[(size_t)m * E_DIM + n] = acc[i][j][r] + bv;
        }
      }
    }
  }
}

// Attention v5 (unchanged this round): all-f16, 64 q per wave, S^T = K.Q^T
// with permuted key->row mapping, in-register P, V^T staged in-kernel.
__global__ __launch_bounds__(256, 2) void attn_f16(
    const f16_t* __restrict__ Q, const f16_t* __restrict__ K,
    const f16_t* __restrict__ V, f16_t* __restrict__ O) {
  constexpr int KSTR = 70;
  __shared__ __align__(16) f16_t Ks[64 * KSTR];
  __shared__ __align__(16) f16_t Vs[64 * KSTR];
  __shared__ float Ls[4][64];

  const int tid = threadIdx.x;
  const int lane = tid & 63;
  const int w = tid >> 6;
  const int quad = lane >> 4;
  const int l16 = lane & 15;
  const int bh = blockIdx.y;
  const int q0 = blockIdx.x * 256 + w * 64;

  const f16_t* Qb = Q + (size_t)bh * L_DIM * HD;
  const f16_t* Kb = K + (size_t)bh * L_DIM * HD;
  const f16_t* Vb = V + (size_t)bh * L_DIM * HD;

  f16x8 qf[4][2];
#pragma unroll
  for (int nt = 0; nt < 4; ++nt)
#pragma unroll
    for (int kc = 0; kc < 2; ++kc)
      qf[nt][kc] = *(const f16x8*)(Qb + (size_t)(q0 + nt * 16 + l16) * HD + kc * 32 + quad * 8);

  f32x4 oacc[4][4] = {};
  float rsum[4] = {0.0f, 0.0f, 0.0f, 0.0f};

  const int sr = tid >> 3;
  const int sc8 = (tid & 7) * 8;
  const int va = tid & 31;
  const int vg = tid >> 5;
  const int rA = (l16 >> 2) * 8 + (l16 & 3);

  for (int kt = 0; kt < 16; ++kt) {
    __syncthreads();
    {
      const f16_t* kp = Kb + (size_t)(kt * 64) * HD;
#pragma unroll
      for (int rr = 0; rr < 2; ++rr) {
        const int row = sr + rr * 32;
        *(f16x8*)&Ks[row * KSTR + sc8] = *(const f16x8*)(kp + (size_t)row * HD + sc8);
      }
      const f16_t* vp = Vb + (size_t)(kt * 64 + vg * 8) * HD + 2 * va;
      unsigned int vd[8];
#pragma unroll
      for (int i = 0; i < 8; ++i) vd[i] = *(const unsigned int*)(vp + (size_t)i * HD);
      union { unsigned int u[4]; f16x8 v; } lo, hi;
#pragma unroll
      for (int i = 0; i < 4; ++i) {
        lo.u[i] = (vd[2 * i] & 0xffffu) | (vd[2 * i + 1] << 16);
        hi.u[i] = (vd[2 * i] >> 16) | (vd[2 * i + 1] & 0xffff0000u);
      }
      *(f16x8*)&Vs[(2 * va) * KSTR + vg * 8] = lo.v;
      *(f16x8*)&Vs[(2 * va + 1) * KSTR + vg * 8] = hi.v;
    }
    __syncthreads();

#pragma unroll
    for (int c = 0; c < 2; ++c) {
      f32x4 sc[2][4] = {};
#pragma unroll
      for (int h = 0; h < 2; ++h) {
        const int row = c * 32 + h * 4 + rA;
#pragma unroll
        for (int kc = 0; kc < 2; ++kc) {
          const f16x8 ka = *(const f16x8*)&Ks[row * KSTR + kc * 32 + quad * 8];
#pragma unroll
          for (int nt = 0; nt < 4; ++nt)
            sc[h][nt] = __builtin_amdgcn_mfma_f32_16x16x32_f16(ka, qf[nt][kc], sc[h][nt], 0, 0, 0);
        }
      }

      f16x8 pa[4];
#pragma unroll
      for (int nt = 0; nt < 4; ++nt)
#pragma unroll
        for (int h = 0; h < 2; ++h)
#pragma unroll
          for (int r = 0; r < 4; ++r) {
            const float e = __expf(sc[h][nt][r]);
            rsum[nt] += e;
            pa[nt][h * 4 + r] = (f16_t)e;
          }

#pragma unroll
      for (int nd = 0; nd < 4; ++nd) {
        const f16x8 vb = *(const f16x8*)&Vs[(nd * 16 + l16) * KSTR + c * 32 + quad * 8];
#pragma unroll
        for (int nt = 0; nt < 4; ++nt)
          oacc[nt][nd] = __builtin_amdgcn_mfma_f32_16x16x32_f16(pa[nt], vb, oacc[nt][nd], 0, 0, 0);
      }
    }
  }

#pragma unroll
  for (int nt = 0; nt < 4; ++nt) {
    float rs = rsum[nt];
    rs += __shfl_xor(rs, 16); rs += __shfl_xor(rs, 32);
    if (quad == 0) Ls[w][nt * 16 + l16] = rs;
  }
  asm volatile("s_waitcnt lgkmcnt(0)" ::: "memory");

  const int b = bh >> 4;
  const int h = bh & 15;
#pragma unroll
  for (int nt = 0; nt < 4; ++nt)
#pragma unroll
    for (int r = 0; r < 4; ++r) {
      const int ql = nt * 16 + quad * 4 + r;
      const float inv = 1.0f / Ls[w][ql];
      const int qrow = q0 + ql;
#pragma unroll
      for (int nd = 0; nd < 4; ++nd) {
        const int d = nd * 16 + l16;
        O[((size_t)qrow * B_DIM + b) * E_DIM + h * HD + d] = (f16_t)(oacc[nt][nd][r] * inv);
      }
    }
}

extern "C" void kernel_launch(void* const* d_in, const int* in_sizes, int n_in,
                              void* d_out, int out_size, void* d_ws, size_t ws_size,
                              hipStream_t stream) {
  const float* x     = (const float*)d_in[0];
  const float* w_in  = (const float*)d_in[1];
  const float* b_in  = (const float*)d_in[2];
  const float* w_out = (const float*)d_in[3];
  const float* b_out = (const float*)d_in[4];

  const size_t TS = (size_t)BH_DIM * L_DIM * HD;  // 8M elements per tensor
  f16_t* q16  = (f16_t*)d_ws;
  f16_t* k16  = q16 + TS;
  f16_t* v16  = k16 + TS;
  f16_t* x16  = v16 + TS;
  f16_t* wi16 = x16 + TS;
  f16_t* wo16 = wi16 + (size_t)3 * E_DIM * E_DIM;
  f16_t* ao16 = x16;   // alias: x16 dead after QKV GEMM

  // 0) fp32 -> f16 pre-convert (x, w_in, w_out)
  convert_f16<<<4096, 256, 0, stream>>>(x, w_in, w_out, x16, wi16, wo16);
  // 1) QKV projection: 128^2 dbuf BK=64, 2 blocks/CU, grid 1536 (3x512 exact)
  gemm_qkv<<<1536, 256, 0, stream>>>(x16, wi16, b_in, q16, k16, v16);
  // 2) attention: 128 (b,h) x 4 q-blocks of 256
  attn_f16<<<dim3(4, 128), 256, 0, stream>>>(q16, k16, v16, ao16);
  // 3) out projection: [8192,1024] x [1024,1024]^T -> fp32 d_out
  gemm_f16<1><<<dim3(8, 64), 256, 0, stream>>>(ao16, wo16, b_out, d_out, nullptr, nullptr);
}